// Round 3
// baseline (111.940 us; speedup 1.0000x reference)
//
#include <hip/hip_runtime.h>

// SNN policy rollout, fully fused. B=32768 rows, H=64 hidden, O=4 outputs, T=16 steps.
// Mapping: 256-thread block = 4 waves = 32 rows. Per wave: 8 rows x 8 lanes/row,
// each lane owns 8 h-channels (h = li*8 .. li*8+7, contiguous for float4 loads).
// All recurrent state in registers; ia-reduction via 3-step __shfl_xor butterfly
// within each 8-lane row group; softmax over O=4 replicated across the row group.
// val output is exactly 16.0 (softmax of a [B,1] tensor is bitwise 1.0).
//
// Numerics: the spike threshold (mem - Bth) > 0 is discontinuous, so the
// recurrence is written with `#pragma clang fp contract(off)` in the exact
// reference op order (XLA emits non-contracted fmul/fadd for elementwise HLO;
// hipcc's default -ffp-contract=fast would fuse and drift ~1 ULP/step).

constexpr int H_DIM = 64;
constexpr int IN_DIM = 8;
constexpr int O_DIM = 4;
constexpr int TSTEPS = 16;

__global__ __launch_bounds__(256, 4) void snn_fused(
    const float* __restrict__ x,           // [B,8]
    const float* __restrict__ W1,          // [64,8]
    const float* __restrict__ b1,          // [64]
    const float* __restrict__ Wa,          // [4,64]
    const float* __restrict__ ba,          // [4]
    const float* __restrict__ tau_adp_h1,  // [64]
    const float* __restrict__ tau_m_h1,    // [64]
    const float* __restrict__ tau_m_a,     // [4]
    const float* __restrict__ hid1_mem0,   // [B,64]
    const float* __restrict__ a_out_mem0,  // [B,4]
    float* __restrict__ out_val,           // [B]
    float* __restrict__ out_act,           // [B,4]
    int B)
{
    const int lane = threadIdx.x & 63;
    const int li   = lane & 7;   // lane within row-group
    const int sub  = lane >> 3;  // row within wave
    const int gw   = (blockIdx.x * blockDim.x + threadIdx.x) >> 6;
    const int row  = gw * 8 + sub;
    if (row >= B) return;

    const int h0 = li * 8;

    float alpha[8], ro[8], omro[8], ch[8];
    float wa0[8], wa1[8], wa2[8], wa3[8];
    float mem[8], bb[8], spk[8];

    {
        float4 t0 = *(const float4*)(tau_m_h1 + h0);
        float4 t1 = *(const float4*)(tau_m_h1 + h0 + 4);
        float tm[8] = {t0.x, t0.y, t0.z, t0.w, t1.x, t1.y, t1.z, t1.w};
        float4 a0 = *(const float4*)(tau_adp_h1 + h0);
        float4 a1 = *(const float4*)(tau_adp_h1 + h0 + 4);
        float td[8] = {a0.x, a0.y, a0.z, a0.w, a1.x, a1.y, a1.z, a1.w};
#pragma unroll
        for (int k = 0; k < 8; ++k) {
            alpha[k] = expf(-1.0f / tm[k]);   // accurate exp: feeds the spike threshold path
            ro[k]    = expf(-1.0f / td[k]);
            omro[k]  = 1.0f - ro[k];
        }
    }

    // ---- input projection: inpt = x @ W1.T + b1 ; ch = (1-alpha)*R_M*inpt ----
    {
#pragma clang fp contract(off)
        float4 xa = *(const float4*)(x + (size_t)row * IN_DIM);
        float4 xb = *(const float4*)(x + (size_t)row * IN_DIM + 4);
        float4 bv0 = *(const float4*)(b1 + h0);
        float4 bv1 = *(const float4*)(b1 + h0 + 4);
        float b1v[8] = {bv0.x, bv0.y, bv0.z, bv0.w, bv1.x, bv1.y, bv1.z, bv1.w};
#pragma unroll
        for (int k = 0; k < 8; ++k) {
            float4 w_0 = *(const float4*)(W1 + (h0 + k) * IN_DIM);
            float4 w_1 = *(const float4*)(W1 + (h0 + k) * IN_DIM + 4);
            // dot over IN=8: XLA's dot uses fma; keep fmaf here.
            float ip = b1v[k];
            ip = fmaf(xa.x, w_0.x, ip); ip = fmaf(xa.y, w_0.y, ip);
            ip = fmaf(xa.z, w_0.z, ip); ip = fmaf(xa.w, w_0.w, ip);
            ip = fmaf(xb.x, w_1.x, ip); ip = fmaf(xb.y, w_1.y, ip);
            ip = fmaf(xb.z, w_1.z, ip); ip = fmaf(xb.w, w_1.w, ip);
            ch[k] = (1.0f - alpha[k]) * ip;   // (1-a)*R_M*inpt, R_M==1.0 (exact)
        }
    }

    // ---- Wa fragments: lane holds Wa[o][h0..h0+7] for o=0..3 ----
#define LOADW(dst, o)                                              \
    {                                                              \
        float4 p0 = *(const float4*)(Wa + (o) * H_DIM + h0);       \
        float4 p1 = *(const float4*)(Wa + (o) * H_DIM + h0 + 4);   \
        dst[0] = p0.x; dst[1] = p0.y; dst[2] = p0.z; dst[3] = p0.w;\
        dst[4] = p1.x; dst[5] = p1.y; dst[6] = p1.z; dst[7] = p1.w;\
    }
    LOADW(wa0, 0) LOADW(wa1, 1) LOADW(wa2, 2) LOADW(wa3, 3)
#undef LOADW

    {
        float4 m0 = *(const float4*)(hid1_mem0 + (size_t)row * H_DIM + h0);
        float4 m1 = *(const float4*)(hid1_mem0 + (size_t)row * H_DIM + h0 + 4);
        mem[0] = m0.x; mem[1] = m0.y; mem[2] = m0.z; mem[3] = m0.w;
        mem[4] = m1.x; mem[5] = m1.y; mem[6] = m1.z; mem[7] = m1.w;
#pragma unroll
        for (int k = 0; k < 8; ++k) { spk[k] = 0.0f; bb[k] = 0.01f; }
    }

    float al_a[4], oma_a[4], bav[4], am[4], acc[4];
    {
        float4 ta = *(const float4*)(tau_m_a);
        al_a[0] = expf(-1.0f / ta.x); al_a[1] = expf(-1.0f / ta.y);
        al_a[2] = expf(-1.0f / ta.z); al_a[3] = expf(-1.0f / ta.w);
#pragma unroll
        for (int o = 0; o < 4; ++o) oma_a[o] = 1.0f - al_a[o];
        float4 bb4 = *(const float4*)(ba);
        bav[0] = bb4.x; bav[1] = bb4.y; bav[2] = bb4.z; bav[3] = bb4.w;
        float4 am4 = *(const float4*)(a_out_mem0 + (size_t)row * O_DIM);
        am[0] = am4.x; am[1] = am4.y; am[2] = am4.z; am[3] = am4.w;
#pragma unroll
        for (int o = 0; o < 4; ++o) acc[o] = 0.0f;
    }

    // ---- T=16 recurrent steps (contract-off, exact reference op order) ----
#pragma unroll 1
    for (int t = 0; t < TSTEPS; ++t) {
#pragma clang fp contract(off)
        float s0 = 0.f, s1 = 0.f, s2 = 0.f, s3 = 0.f;
#pragma unroll
        for (int k = 0; k < 8; ++k) {
            // b = ro*b + (1-ro)*spk_old
            bb[k] = (ro[k] * bb[k]) + (omro[k] * spk[k]);
            // Bth = b_j0 + 1.8*b
            const float Bth = 0.01f + (1.8f * bb[k]);
            // mem = (mem*alpha + (1-alpha)*inpt) - Bth*spk_old
            const float m = ((mem[k] * alpha[k]) + ch[k]) - (Bth * spk[k]);
            mem[k] = m;
            // spike_fn(mem - Bth): subtraction of nearby values is exact,
            // so (m - Bth) > 0  <=>  m > Bth, bitwise-equivalent.
            const float s = (m > Bth) ? 1.0f : 0.0f;
            spk[k] = s;
            // ia partial dot (dot path: fma, like XLA's reduction)
            s0 = fmaf(s, wa0[k], s0);
            s1 = fmaf(s, wa1[k], s1);
            s2 = fmaf(s, wa2[k], s2);
            s3 = fmaf(s, wa3[k], s3);
        }
        // reduce the 4 partial ia sums across the 8 lanes of this row
#pragma unroll
        for (int msk = 1; msk < 8; msk <<= 1) {
            s0 += __shfl_xor(s0, msk);
            s1 += __shfl_xor(s1, msk);
            s2 += __shfl_xor(s2, msk);
            s3 += __shfl_xor(s3, msk);
        }
        // a_mem = a_mem*alpha_a + (1-alpha_a)*(ia+ba)   (all 8 lanes identical)
        am[0] = (al_a[0] * am[0]) + (oma_a[0] * (s0 + bav[0]));
        am[1] = (al_a[1] * am[1]) + (oma_a[1] * (s1 + bav[1]));
        am[2] = (al_a[2] * am[2]) + (oma_a[2] * (s2 + bav[2]));
        am[3] = (al_a[3] * am[3]) + (oma_a[3] * (s3 + bav[3]));
        const float mx = fmaxf(fmaxf(am[0], am[1]), fmaxf(am[2], am[3]));
        const float e0 = __expf(am[0] - mx);
        const float e1 = __expf(am[1] - mx);
        const float e2 = __expf(am[2] - mx);
        const float e3 = __expf(am[3] - mx);
        const float S = ((e0 + e1) + e2) + e3;
        const float r = 1.0f / S;               // precise divide (continuous path)
        acc[0] = acc[0] + (e0 * r);
        acc[1] = acc[1] + (e1 * r);
        acc[2] = acc[2] + (e2 * r);
        acc[3] = acc[3] + (e3 * r);
    }

    if (li == 0) {
        out_val[row] = 16.0f;  // softmax of a single logit is bitwise 1.0, x16 steps
        *(float4*)(out_act + (size_t)row * O_DIM) =
            make_float4(acc[0], acc[1], acc[2], acc[3]);
    }
}

extern "C" void kernel_launch(void* const* d_in, const int* in_sizes, int n_in,
                              void* d_out, int out_size, void* d_ws, size_t ws_size,
                              hipStream_t stream) {
    // setup_inputs() order:
    //  0:x 1:W1 2:b1 3:Wa 4:ba 5:Wc(dead) 6:bc(dead) 7:tau_adp_h1 8:tau_m_h1
    //  9:tau_m_a 10:tau_m_c(dead) 11:hid1_mem0 12:a_out_mem0 13:c_out_mem0(dead)
    const float* x          = (const float*)d_in[0];
    const float* W1         = (const float*)d_in[1];
    const float* b1         = (const float*)d_in[2];
    const float* Wa         = (const float*)d_in[3];
    const float* ba         = (const float*)d_in[4];
    const float* tau_adp_h1 = (const float*)d_in[7];
    const float* tau_m_h1   = (const float*)d_in[8];
    const float* tau_m_a    = (const float*)d_in[9];
    const float* hid1_mem0  = (const float*)d_in[11];
    const float* a_out_mem0 = (const float*)d_in[12];

    const int B = in_sizes[11] / H_DIM;   // from hid1_mem0 [B,64] -> 32768
    float* out_val = (float*)d_out;       // [B]  (val, flattened [B,1])
    float* out_act = (float*)d_out + B;   // [B,4]

    const int rows_per_block = 32;        // 256 threads = 4 waves x 8 rows
    const int blocks = (B + rows_per_block - 1) / rows_per_block;
    snn_fused<<<blocks, 256, 0, stream>>>(x, W1, b1, Wa, ba, tau_adp_h1,
                                          tau_m_h1, tau_m_a, hid1_mem0,
                                          a_out_mem0, out_val, out_act, B);
}